// Round 1
// baseline (270.083 us; speedup 1.0000x reference)
//
#include <hip/hip_runtime.h>
#include <math.h>

// Problem constants
constexpr int B_  = 4;
constexpr int L_  = 8192;
constexpr int D_  = 128;
constexpr int N_  = 32;
constexpr int BL  = B_ * L_;          // 32768 rows
constexpr int CH  = 32;               // scan chunk rows
constexpr int NC  = L_ / CH;          // 256 chunks per batch

// ---------------------------------------------------------------------------
// Generic K=128 f32 GEMM: C = A(Mx128) @ B(128xN), tile 128x64, 256 threads.
// MODE 0: split columns -> C0 (cols 0..127, ld 128), C1 (128..159, ld 32),
//         C2 (160..191, ld 32).      (x @ W_x  -> delta_raw | Bm | Cm)
// MODE 1: C0 = softplus(v + bias)    (delta_raw @ W_dt -> delta)
// MODE 2: C0 = relu(v + bias)        (h_t @ W_f -> ssm)
// ---------------------------------------------------------------------------
template <int MODE>
__global__ __launch_bounds__(256) void gemm_k128(
    const float* __restrict__ A, const float* __restrict__ Bm,
    const float* __restrict__ bias,
    float* __restrict__ C0, float* __restrict__ C1, float* __restrict__ C2,
    int N)
{
    __shared__ float As[32][132];   // As[k][row], transposed A tile (128 rows)
    __shared__ float Bs[32][68];    // Bs[k][col], 64 cols

    const int tid = threadIdx.x;
    const int r0  = blockIdx.x * 128;
    const int cb  = blockIdx.y * 64;
    const int ty  = tid >> 4;       // 0..15 -> 8 rows each
    const int tx  = tid & 15;       // 0..15 -> 4 cols each

    float acc[8][4];
    #pragma unroll
    for (int i = 0; i < 8; ++i)
        #pragma unroll
        for (int j = 0; j < 4; ++j) acc[i][j] = 0.f;

    for (int kt = 0; kt < 128; kt += 32) {
        // stage A tile transposed: rows r0..r0+127, k = kt..kt+31
        {
            const int row = tid >> 3;       // 0..31
            const int kv  = tid & 7;        // 0..7 (float4 group)
            #pragma unroll
            for (int j = 0; j < 4; ++j) {
                const int r = row + j * 32;
                float4 v = *reinterpret_cast<const float4*>(
                    &A[(size_t)(r0 + r) * 128 + kt + kv * 4]);
                As[kv * 4 + 0][r] = v.x;
                As[kv * 4 + 1][r] = v.y;
                As[kv * 4 + 2][r] = v.z;
                As[kv * 4 + 3][r] = v.w;
            }
            const int kr = tid >> 4;        // 0..15
            const int cv = tid & 15;        // 0..15
            #pragma unroll
            for (int j = 0; j < 2; ++j) {
                const int k = kr + j * 16;
                *reinterpret_cast<float4*>(&Bs[k][cv * 4]) =
                    *reinterpret_cast<const float4*>(
                        &Bm[(size_t)(kt + k) * N + cb + cv * 4]);
            }
        }
        __syncthreads();
        #pragma unroll
        for (int k = 0; k < 32; ++k) {
            float a[8], b[4];
            *reinterpret_cast<float4*>(&a[0]) =
                *reinterpret_cast<const float4*>(&As[k][ty * 8]);
            *reinterpret_cast<float4*>(&a[4]) =
                *reinterpret_cast<const float4*>(&As[k][ty * 8 + 4]);
            *reinterpret_cast<float4*>(&b[0]) =
                *reinterpret_cast<const float4*>(&Bs[k][tx * 4]);
            #pragma unroll
            for (int i = 0; i < 8; ++i) {
                acc[i][0] = fmaf(a[i], b[0], acc[i][0]);
                acc[i][1] = fmaf(a[i], b[1], acc[i][1]);
                acc[i][2] = fmaf(a[i], b[2], acc[i][2]);
                acc[i][3] = fmaf(a[i], b[3], acc[i][3]);
            }
        }
        __syncthreads();
    }

    const int c = cb + tx * 4;
    float4 bv = make_float4(0.f, 0.f, 0.f, 0.f);
    if (MODE != 0) bv = *reinterpret_cast<const float4*>(&bias[c]);

    #pragma unroll
    for (int i = 0; i < 8; ++i) {
        const int r = r0 + ty * 8 + i;
        float4 o;
        o.x = acc[i][0]; o.y = acc[i][1]; o.z = acc[i][2]; o.w = acc[i][3];
        if (MODE == 0) {
            if (c < 128)
                *reinterpret_cast<float4*>(&C0[(size_t)r * 128 + c]) = o;
            else if (c < 160)
                *reinterpret_cast<float4*>(&C1[(size_t)r * 32 + (c - 128)]) = o;
            else
                *reinterpret_cast<float4*>(&C2[(size_t)r * 32 + (c - 160)]) = o;
        } else if (MODE == 1) {
            o.x += bv.x; o.y += bv.y; o.z += bv.z; o.w += bv.w;
            // stable softplus
            o.x = fmaxf(o.x, 0.f) + log1pf(expf(-fabsf(o.x)));
            o.y = fmaxf(o.y, 0.f) + log1pf(expf(-fabsf(o.y)));
            o.z = fmaxf(o.z, 0.f) + log1pf(expf(-fabsf(o.z)));
            o.w = fmaxf(o.w, 0.f) + log1pf(expf(-fabsf(o.w)));
            *reinterpret_cast<float4*>(&C0[(size_t)r * 128 + c]) = o;
        } else {
            o.x = fmaxf(o.x + bv.x, 0.f);
            o.y = fmaxf(o.y + bv.y, 0.f);
            o.z = fmaxf(o.z + bv.z, 0.f);
            o.w = fmaxf(o.w + bv.w, 0.f);
            *reinterpret_cast<float4*>(&C0[(size_t)r * 128 + c]) = o;
        }
    }
}

// ---------------------------------------------------------------------------
// Scan step 1: per-chunk column sums of delta. grid (NC, B), 128 threads.
// ---------------------------------------------------------------------------
__global__ __launch_bounds__(128) void scan_partial(
    const float* __restrict__ delta, float* __restrict__ part)
{
    const int c = blockIdx.x, b = blockIdx.y, d = threadIdx.x;
    const float* p = delta + ((size_t)b * L_ + (size_t)c * CH) * D_ + d;
    float s = 0.f;
    #pragma unroll
    for (int i = 0; i < CH; ++i) s += p[(size_t)i * D_];
    part[((size_t)b * NC + c) * D_ + d] = s;
}

// ---------------------------------------------------------------------------
// Scan step 2: exclusive prefix over chunks, per (b,d). grid (B), 128 thr.
// ---------------------------------------------------------------------------
__global__ __launch_bounds__(128) void scan_prefix(float* __restrict__ part)
{
    const int b = blockIdx.x, d = threadIdx.x;
    float run = 0.f;
    for (int c = 0; c < NC; ++c) {
        const size_t idx = ((size_t)b * NC + c) * D_ + d;
        const float v = part[idx];
        part[idx] = run;
        run += v;
    }
}

// ---------------------------------------------------------------------------
// Scan step 3 (main): h_t[b,l,d] = (1+Dp[d]) * delta*hprev *
//                     sum_n Bm[l,n]*Cm[l,n]*exp(S_excl[b,l,d]*A[d,n])
// grid (NC, B), 128 threads (one per d). Writes h_t to d_out second half.
// ---------------------------------------------------------------------------
__global__ __launch_bounds__(128) void scan_main(
    const float* __restrict__ delta, const float* __restrict__ hprev,
    const float* __restrict__ Bmat, const float* __restrict__ Cmat,
    const float* __restrict__ A_log, const float* __restrict__ Dp,
    const float* __restrict__ part, float* __restrict__ h_out)
{
    const int c = blockIdx.x, b = blockIdx.y, d = threadIdx.x;
    const int lane = threadIdx.x & 63;

    float a[N_];
    #pragma unroll
    for (int n = 0; n < N_; ++n) a[n] = -expf(A_log[d * N_ + n]);
    const float dp1 = 1.f + Dp[d];

    float s = part[((size_t)b * NC + c) * D_ + d];
    const size_t rowbase = (size_t)b * L_ + (size_t)c * CH;

    for (int i = 0; i < CH; ++i) {
        const size_t row = rowbase + i;
        const float dv = delta[row * D_ + d];
        const float hv = hprev[row * D_ + d];
        const float bc = Bmat[row * N_ + (lane & 31)] * Cmat[row * N_ + (lane & 31)];
        float accv = 0.f;
        #pragma unroll
        for (int n = 0; n < N_; ++n) {
            const float bcn = __shfl(bc, n, 64);
            accv = fmaf(bcn, __expf(s * a[n]), accv);
        }
        h_out[row * D_ + d] = dv * hv * accv * dp1;
        s += dv;   // exclusive cumsum: use then add
    }
}

// ---------------------------------------------------------------------------
// Causal conv (k=3) as GEMM over taps + relu + fuse-multiply.
// grid (L/128, 2, B), 256 threads. out = ssm * relu(conv(ssm) + bias)
// ---------------------------------------------------------------------------
__global__ __launch_bounds__(256) void conv_fuse(
    const float* __restrict__ ssm, const float* __restrict__ Wc,
    const float* __restrict__ cbias, float* __restrict__ fused)
{
    __shared__ float As[32][136];     // As[k][j]: j=0..129 -> row r0-2+j
    __shared__ float Bs[3][32][68];

    const int tid = threadIdx.x;
    const int b  = blockIdx.z;
    const int r0 = blockIdx.x * 128;  // row within batch
    const int cb = blockIdx.y * 64;
    const int ty = tid >> 4, tx = tid & 15;
    const float* sb = ssm + (size_t)b * L_ * D_;

    float acc[8][4];
    #pragma unroll
    for (int i = 0; i < 8; ++i)
        #pragma unroll
        for (int j = 0; j < 4; ++j) acc[i][j] = 0.f;

    for (int kt = 0; kt < 128; kt += 32) {
        {
            const int row = tid >> 3, kv = tid & 7;
            #pragma unroll
            for (int j = 0; j < 5; ++j) {
                const int rr = row + j * 32;
                if (rr < 130) {
                    const int g = r0 - 2 + rr;
                    float4 v = make_float4(0.f, 0.f, 0.f, 0.f);
                    if (g >= 0)
                        v = *reinterpret_cast<const float4*>(
                            &sb[(size_t)g * D_ + kt + kv * 4]);
                    As[kv * 4 + 0][rr] = v.x;
                    As[kv * 4 + 1][rr] = v.y;
                    As[kv * 4 + 2][rr] = v.z;
                    As[kv * 4 + 3][rr] = v.w;
                }
            }
            const int kr = tid >> 4, cv = tid & 15;
            #pragma unroll
            for (int w = 0; w < 3; ++w)
                #pragma unroll
                for (int j = 0; j < 2; ++j) {
                    const int k = kr + j * 16;
                    *reinterpret_cast<float4*>(&Bs[w][k][cv * 4]) =
                        *reinterpret_cast<const float4*>(
                            &Wc[((size_t)w * 128 + kt + k) * 128 + cb + cv * 4]);
                }
        }
        __syncthreads();
        #pragma unroll
        for (int k = 0; k < 32; ++k) {
            float a12[12];
            *reinterpret_cast<float4*>(&a12[0]) =
                *reinterpret_cast<const float4*>(&As[k][ty * 8]);
            *reinterpret_cast<float4*>(&a12[4]) =
                *reinterpret_cast<const float4*>(&As[k][ty * 8 + 4]);
            *reinterpret_cast<float4*>(&a12[8]) =
                *reinterpret_cast<const float4*>(&As[k][ty * 8 + 8]);
            #pragma unroll
            for (int w = 0; w < 3; ++w) {
                float4 bw = *reinterpret_cast<const float4*>(&Bs[w][k][tx * 4]);
                #pragma unroll
                for (int i = 0; i < 8; ++i) {
                    const float av = a12[i + w];
                    acc[i][0] = fmaf(av, bw.x, acc[i][0]);
                    acc[i][1] = fmaf(av, bw.y, acc[i][1]);
                    acc[i][2] = fmaf(av, bw.z, acc[i][2]);
                    acc[i][3] = fmaf(av, bw.w, acc[i][3]);
                }
            }
        }
        __syncthreads();
    }

    const int c = cb + tx * 4;
    const float4 bv = *reinterpret_cast<const float4*>(&cbias[c]);
    #pragma unroll
    for (int i = 0; i < 8; ++i) {
        const int r = r0 + ty * 8 + i;
        const float4 sv = *reinterpret_cast<const float4*>(&sb[(size_t)r * D_ + c]);
        float4 o;
        o.x = sv.x * fmaxf(acc[i][0] + bv.x, 0.f);
        o.y = sv.y * fmaxf(acc[i][1] + bv.y, 0.f);
        o.z = sv.z * fmaxf(acc[i][2] + bv.z, 0.f);
        o.w = sv.w * fmaxf(acc[i][3] + bv.w, 0.f);
        *reinterpret_cast<float4*>(&fused[((size_t)b * L_ + r) * D_ + c]) = o;
    }
}

// ---------------------------------------------------------------------------
extern "C" void kernel_launch(void* const* d_in, const int* in_sizes, int n_in,
                              void* d_out, int out_size, void* d_ws, size_t ws_size,
                              hipStream_t stream)
{
    const float* x      = (const float*)d_in[0];
    const float* hprev  = (const float*)d_in[1];
    const float* A_log  = (const float*)d_in[2];
    const float* Dp     = (const float*)d_in[3];
    const float* W_x    = (const float*)d_in[4];
    const float* W_dt   = (const float*)d_in[5];
    const float* b_dt   = (const float*)d_in[6];
    const float* conv_w = (const float*)d_in[7];
    const float* conv_b = (const float*)d_in[8];
    const float* W_f    = (const float*)d_in[9];
    const float* b_f    = (const float*)d_in[10];

    float* out   = (float*)d_out;                       // fused_output
    float* h_out = out + (size_t)BL * D_;               // h_t

    float* ws    = (float*)d_ws;
    float* draw  = ws;                                  // delta_raw, later ssm
    float* delta = ws + (size_t)BL * D_;
    float* Bmb   = delta + (size_t)BL * D_;
    float* Cmb   = Bmb + (size_t)BL * N_;
    float* part  = Cmb + (size_t)BL * N_;
    float* ssm   = draw;                                // reuse (draw dead)

    dim3 blk(256);
    // 1) x_dbl = x @ W_x  -> delta_raw | Bm | Cm
    gemm_k128<0><<<dim3(BL / 128, 3), blk, 0, stream>>>(
        x, W_x, nullptr, draw, Bmb, Cmb, 192);
    // 2) delta = softplus(delta_raw @ W_dt + b_dt)
    gemm_k128<1><<<dim3(BL / 128, 2), blk, 0, stream>>>(
        draw, W_dt, b_dt, delta, nullptr, nullptr, 128);
    // 3-4) exclusive cumsum of delta over L (chunked)
    scan_partial<<<dim3(NC, B_), dim3(128), 0, stream>>>(delta, part);
    scan_prefix<<<dim3(B_), dim3(128), 0, stream>>>(part);
    // 5) selective-scan main: writes h_t
    scan_main<<<dim3(NC, B_), dim3(128), 0, stream>>>(
        delta, hprev, Bmb, Cmb, A_log, Dp, part, h_out);
    // 6) ssm = relu(h_t @ W_f + b_f)
    gemm_k128<2><<<dim3(BL / 128, 2), blk, 0, stream>>>(
        h_out, W_f, b_f, ssm, nullptr, nullptr, 128);
    // 7) fused = ssm * relu(causal_conv3(ssm) + conv_b)
    conv_fuse<<<dim3(L_ / 128, 2, B_), blk, 0, stream>>>(
        ssm, conv_w, conv_b, out);
}

// Round 2
// 181.617 us; speedup vs baseline: 1.4871x; 1.4871x over previous
//
#include <hip/hip_runtime.h>
#include <math.h>

typedef unsigned short ushort_t;
typedef __attribute__((ext_vector_type(8))) short short8v;   // 8 bf16
typedef __attribute__((ext_vector_type(4))) float f32x4;

// Problem constants
constexpr int B_  = 4;
constexpr int L_  = 8192;
constexpr int D_  = 128;
constexpr int N_  = 32;
constexpr int BL  = B_ * L_;          // 32768 rows
constexpr int CH  = 32;               // scan chunk rows
constexpr int NC  = L_ / CH;          // 256 chunks per batch

// round-to-nearest-even f32 -> bf16, packed pair (a in low 16)
__device__ inline unsigned bfr(float x) {
    unsigned u = __float_as_uint(x);
    return (u + 0x7fffu + ((u >> 16) & 1u)) >> 16;
}
__device__ inline unsigned pkbf(float a, float b) {
    return bfr(a) | (bfr(b) << 16);
}

// ---------------------------------------------------------------------------
// prep: transpose+convert weights to bf16 [N][K=128]; negA = -exp(A_log).
// blockIdx.y: 0=W_x(192) 1=W_dt(128) 2=W_f(128) 3..5=conv taps(128) 6=negA
// ---------------------------------------------------------------------------
__global__ __launch_bounds__(256) void prep(
    const float* __restrict__ Wx, const float* __restrict__ Wdt,
    const float* __restrict__ Wf, const float* __restrict__ Wconv,
    const float* __restrict__ A_log,
    ushort_t* __restrict__ Wt0, ushort_t* __restrict__ Wt1,
    ushort_t* __restrict__ Wt2, ushort_t* __restrict__ Wtc,
    float* __restrict__ negA)
{
    const int which = blockIdx.y;
    const int t = blockIdx.x * 256 + threadIdx.x;
    if (which == 6) {
        if (t < D_ * N_) negA[t] = -expf(A_log[t]);
        return;
    }
    const float* src; ushort_t* dst; int N;
    switch (which) {
        case 0: src = Wx;  dst = Wt0; N = 192; break;
        case 1: src = Wdt; dst = Wt1; N = 128; break;
        case 2: src = Wf;  dst = Wt2; N = 128; break;
        default:
            src = Wconv + (size_t)(which - 3) * 128 * 128;
            dst = Wtc  + (size_t)(which - 3) * 128 * 128;
            N = 128; break;
    }
    if (t >= N * 32) return;
    const int n = t >> 5, k4 = (t & 31) * 4;
    const float a0 = src[(size_t)(k4 + 0) * N + n];
    const float a1 = src[(size_t)(k4 + 1) * N + n];
    const float a2 = src[(size_t)(k4 + 2) * N + n];
    const float a3 = src[(size_t)(k4 + 3) * N + n];
    uint2 p; p.x = pkbf(a0, a1); p.y = pkbf(a2, a3);
    *reinterpret_cast<uint2*>(&dst[(size_t)n * 128 + k4]) = p;
}

// ---------------------------------------------------------------------------
// bf16 MFMA GEMM: C(Mx NCOLS) = A(Mx128) @ W(128 x NCOLS), W pre-transposed
// bf16 [NCOLS][128]. BM=64, BK=64 (2 steps), 256 threads = 4 waves (2x2).
// MODE 0: split cols -> C0(0..127), C1(128..159), C2(160..191)
// MODE 1: C0 = softplus(v + bias)
// MODE 2: C0 = relu(v + bias)
// ---------------------------------------------------------------------------
template <int NCOLS, int MODE>
__global__ __launch_bounds__(256) void gemm_mfma(
    const float* __restrict__ Ag, const ushort_t* __restrict__ Wt,
    const float* __restrict__ bias,
    float* __restrict__ C0, float* __restrict__ C1, float* __restrict__ C2)
{
    __shared__ __align__(16) ushort_t Alds[64 * 64];
    __shared__ __align__(16) ushort_t Blds[NCOLS * 64];

    const int tid  = threadIdx.x;
    const int r0   = blockIdx.x * 64;
    const int wid  = tid >> 6, lane = tid & 63;
    const int wm   = wid >> 1, wn = wid & 1;
    const int lr   = lane & 15, kg = lane >> 4;      // kg 0..3
    constexpr int NF = NCOLS / 32;                   // n-frags per wave

    f32x4 acc[2][NF] = {};

    for (int kt = 0; kt < 128; kt += 64) {
        // stage A (64 rows x 64 k), f32 -> bf16, XOR-swizzled
        #pragma unroll
        for (int j = 0; j < 2; ++j) {
            const int g = tid + j * 256;             // 512 groups of 8
            const int row = g >> 3, k8 = (g & 7) * 8;
            const float* src = &Ag[(size_t)(r0 + row) * 128 + kt + k8];
            const float4 v0 = *reinterpret_cast<const float4*>(src);
            const float4 v1 = *reinterpret_cast<const float4*>(src + 4);
            uint4 p;
            p.x = pkbf(v0.x, v0.y); p.y = pkbf(v0.z, v0.w);
            p.z = pkbf(v1.x, v1.y); p.w = pkbf(v1.z, v1.w);
            *reinterpret_cast<uint4*>(&Alds[row * 64 + (k8 ^ ((row & 7) << 3))]) = p;
        }
        // stage B (NCOLS rows x 64 k) from bf16 global, XOR-swizzled
        #pragma unroll
        for (int j = 0; j < NCOLS / 32; ++j) {
            const int g = tid + j * 256;
            const int n = g >> 3, k8 = (g & 7) * 8;
            const uint4 p = *reinterpret_cast<const uint4*>(&Wt[(size_t)n * 128 + kt + k8]);
            *reinterpret_cast<uint4*>(&Blds[n * 64 + (k8 ^ ((n & 7) << 3))]) = p;
        }
        __syncthreads();

        #pragma unroll
        for (int ks = 0; ks < 2; ++ks) {
            const int k8 = ks * 32 + kg * 8;
            short8v af[2];
            #pragma unroll
            for (int m = 0; m < 2; ++m) {
                const int row = wm * 32 + m * 16 + lr;
                af[m] = *reinterpret_cast<const short8v*>(
                    &Alds[row * 64 + (k8 ^ ((row & 7) << 3))]);
            }
            #pragma unroll
            for (int n = 0; n < NF; ++n) {
                const int col = wn * (NF * 16) + n * 16 + lr;
                const short8v bf = *reinterpret_cast<const short8v*>(
                    &Blds[col * 64 + (k8 ^ ((col & 7) << 3))]);
                acc[0][n] = __builtin_amdgcn_mfma_f32_16x16x32_bf16(af[0], bf, acc[0][n], 0, 0, 0);
                acc[1][n] = __builtin_amdgcn_mfma_f32_16x16x32_bf16(af[1], bf, acc[1][n], 0, 0, 0);
            }
        }
        __syncthreads();
    }

    const int fq = lane >> 4;
    #pragma unroll
    for (int m = 0; m < 2; ++m) {
        #pragma unroll
        for (int n = 0; n < NF; ++n) {
            const int col = wn * (NF * 16) + n * 16 + lr;
            #pragma unroll
            for (int q = 0; q < 4; ++q) {
                const int row = r0 + wm * 32 + m * 16 + fq * 4 + q;
                float v = acc[m][n][q];
                if (MODE == 0) {
                    if (col < 128)
                        C0[(size_t)row * 128 + col] = v;
                    else if (col < 160)
                        C1[(size_t)row * 32 + (col - 128)] = v;
                    else
                        C2[(size_t)row * 32 + (col - 160)] = v;
                } else if (MODE == 1) {
                    v += bias[col];
                    v = fmaxf(v, 0.f) + log1pf(expf(-fabsf(v)));
                    C0[(size_t)row * 128 + col] = v;
                } else {
                    C0[(size_t)row * 128 + col] = fmaxf(v + bias[col], 0.f);
                }
            }
        }
    }
}

// ---------------------------------------------------------------------------
// Scan step 1: per-chunk column sums of delta. grid (NC, B), 128 threads.
// ---------------------------------------------------------------------------
__global__ __launch_bounds__(128) void scan_partial(
    const float* __restrict__ delta, float* __restrict__ part)
{
    const int c = blockIdx.x, b = blockIdx.y, d = threadIdx.x;
    const float* p = delta + ((size_t)b * L_ + (size_t)c * CH) * D_ + d;
    float s = 0.f;
    #pragma unroll
    for (int i = 0; i < CH; ++i) s += p[(size_t)i * D_];
    part[((size_t)b * NC + c) * D_ + d] = s;
}

// ---------------------------------------------------------------------------
// Scan step 2: parallel exclusive prefix over NC=256 chunks per (b,d).
// grid (B, D), 256 threads (one per chunk).
// ---------------------------------------------------------------------------
__global__ __launch_bounds__(256) void scan_prefix(float* __restrict__ part)
{
    const int b = blockIdx.x, d = blockIdx.y, c = threadIdx.x;
    const int w = threadIdx.x >> 6, lane = threadIdx.x & 63;
    const size_t idx = ((size_t)b * NC + c) * D_ + d;
    const float v = part[idx];
    float s = v;
    #pragma unroll
    for (int off = 1; off < 64; off <<= 1) {
        const float t = __shfl_up(s, off, 64);
        if (lane >= off) s += t;
    }
    __shared__ float wsum[4];
    if (lane == 63) wsum[w] = s;
    __syncthreads();
    float add = 0.f;
    #pragma unroll
    for (int i = 0; i < 4; ++i)
        if (i < w) add += wsum[i];
    part[idx] = s + add - v;   // exclusive
}

// ---------------------------------------------------------------------------
// Scan main: h_t[b,l,d] = (1+Dp[d])*delta*hprev*sum_n B*C*exp(S_excl*negA)
// grid (NC, B), 512 threads: d = tid&127, r0 = tid>>7; each thread does
// rows r0, r0+4, ..., r0+28 (8 rows, independent heavy work).
// ---------------------------------------------------------------------------
__global__ __launch_bounds__(512) void scan_main(
    const float* __restrict__ delta, const float* __restrict__ hprev,
    const float* __restrict__ Bmat, const float* __restrict__ Cmat,
    const float* __restrict__ negA, const float* __restrict__ Dp,
    const float* __restrict__ part, float* __restrict__ h_out)
{
    __shared__ float dv_s[32][128];
    const int c = blockIdx.x, b = blockIdx.y;
    const int tid = threadIdx.x;
    const int d = tid & 127, r0 = tid >> 7;
    const int lane = tid & 63;
    const size_t rowbase = (size_t)b * L_ + (size_t)c * CH;

    // stage delta tile (32x128 f32) -> LDS
    #pragma unroll
    for (int j = 0; j < 2; ++j) {
        const int g = tid + j * 512;         // 1024 float4 groups
        const int row = g >> 5, c4 = (g & 31) * 4;
        *reinterpret_cast<float4*>(&dv_s[row][c4]) =
            *reinterpret_cast<const float4*>(&delta[(rowbase + row) * D_ + c4]);
    }

    float a[N_];
    #pragma unroll
    for (int n4 = 0; n4 < 8; ++n4) {
        const float4 v = *reinterpret_cast<const float4*>(&negA[d * N_ + n4 * 4]);
        a[n4 * 4 + 0] = v.x; a[n4 * 4 + 1] = v.y;
        a[n4 * 4 + 2] = v.z; a[n4 * 4 + 3] = v.w;
    }
    const float dp1 = 1.f + Dp[d];
    __syncthreads();

    // per-thread exclusive prefix for its 8 rows
    float s = part[((size_t)b * NC + c) * D_ + d];
    float sv[8];
    #pragma unroll
    for (int i = 0; i < 32; ++i) {
        if ((i & 3) == r0) sv[i >> 2] = s;
        s += dv_s[i][d];
    }

    #pragma unroll
    for (int r = 0; r < 8; ++r) {
        const int i = r * 4 + r0;
        const size_t row = rowbase + i;
        const float dv = dv_s[i][d];
        const float hv = hprev[row * D_ + d];
        const float bc = Bmat[row * N_ + (lane & 31)] * Cmat[row * N_ + (lane & 31)];
        const float sr = sv[r];
        float p0 = 0.f, p1 = 0.f, p2 = 0.f, p3 = 0.f;
        #pragma unroll
        for (int n = 0; n < N_; n += 4) {
            p0 = fmaf(__shfl(bc, n + 0), __expf(sr * a[n + 0]), p0);
            p1 = fmaf(__shfl(bc, n + 1), __expf(sr * a[n + 1]), p1);
            p2 = fmaf(__shfl(bc, n + 2), __expf(sr * a[n + 2]), p2);
            p3 = fmaf(__shfl(bc, n + 3), __expf(sr * a[n + 3]), p3);
        }
        h_out[row * D_ + d] = dv * hv * ((p0 + p1) + (p2 + p3)) * dp1;
    }
}

// ---------------------------------------------------------------------------
// Causal conv3 (bf16 MFMA) + relu + fuse-multiply.
// grid (L/64, B), 256 threads. BM=64 (+2 halo), BN=128, BK=64 x2.
// ---------------------------------------------------------------------------
__global__ __launch_bounds__(256) void conv_fuse_mfma(
    const float* __restrict__ ssm, const ushort_t* __restrict__ Wtc,
    const float* __restrict__ cbias, float* __restrict__ fused)
{
    __shared__ __align__(16) ushort_t Alds[66 * 64];
    __shared__ __align__(16) ushort_t Blds[3 * 128 * 64];

    const int tid = threadIdx.x;
    const int bb = blockIdx.y;
    const int r0 = blockIdx.x * 64;
    const int wid = tid >> 6, lane = tid & 63;
    const int wm = wid >> 1, wn = wid & 1;
    const int lr = lane & 15, kg = lane >> 4;
    const float* sb = ssm + (size_t)bb * L_ * D_;

    f32x4 acc[2][4] = {};

    for (int kt = 0; kt < 128; kt += 64) {
        // stage A rows -2..63 (66 rows) x 64 k
        #pragma unroll
        for (int j = 0; j < 3; ++j) {
            const int g = tid + j * 256;
            if (g < 66 * 8) {
                const int i = g >> 3, k8 = (g & 7) * 8;
                const int gr = r0 - 2 + i;
                float4 v0 = make_float4(0.f, 0.f, 0.f, 0.f), v1 = v0;
                if (gr >= 0) {
                    const float* src = &sb[(size_t)gr * 128 + kt + k8];
                    v0 = *reinterpret_cast<const float4*>(src);
                    v1 = *reinterpret_cast<const float4*>(src + 4);
                }
                uint4 p;
                p.x = pkbf(v0.x, v0.y); p.y = pkbf(v0.z, v0.w);
                p.z = pkbf(v1.x, v1.y); p.w = pkbf(v1.z, v1.w);
                *reinterpret_cast<uint4*>(&Alds[i * 64 + (k8 ^ ((i & 7) << 3))]) = p;
            }
        }
        // stage B: 3 taps x 128 n x 64 k
        #pragma unroll
        for (int j = 0; j < 12; ++j) {
            const int g = tid + j * 256;                 // 3072 groups
            const int row = g >> 3, k8 = (g & 7) * 8;
            const uint4 p = *reinterpret_cast<const uint4*>(&Wtc[(size_t)row * 128 + kt + k8]);
            *reinterpret_cast<uint4*>(&Blds[row * 64 + (k8 ^ ((row & 7) << 3))]) = p;
        }
        __syncthreads();

        #pragma unroll
        for (int ks = 0; ks < 2; ++ks) {
            const int k8 = ks * 32 + kg * 8;
            short8v af[2][3];
            #pragma unroll
            for (int m = 0; m < 2; ++m)
                #pragma unroll
                for (int w = 0; w < 3; ++w) {
                    const int ri = wm * 32 + m * 16 + lr + w;   // halo-shifted
                    af[m][w] = *reinterpret_cast<const short8v*>(
                        &Alds[ri * 64 + (k8 ^ ((ri & 7) << 3))]);
                }
            #pragma unroll
            for (int n = 0; n < 4; ++n) {
                const int col = wn * 64 + n * 16 + lr;
                #pragma unroll
                for (int w = 0; w < 3; ++w) {
                    const int brow = w * 128 + col;
                    const short8v bf = *reinterpret_cast<const short8v*>(
                        &Blds[brow * 64 + (k8 ^ ((brow & 7) << 3))]);
                    acc[0][n] = __builtin_amdgcn_mfma_f32_16x16x32_bf16(af[0][w], bf, acc[0][n], 0, 0, 0);
                    acc[1][n] = __builtin_amdgcn_mfma_f32_16x16x32_bf16(af[1][w], bf, acc[1][n], 0, 0, 0);
                }
            }
        }
        __syncthreads();
    }

    const int fq = lane >> 4;
    #pragma unroll
    for (int m = 0; m < 2; ++m)
        #pragma unroll
        for (int n = 0; n < 4; ++n) {
            const int col = wn * 64 + n * 16 + lr;
            #pragma unroll
            for (int q = 0; q < 4; ++q) {
                const int row = r0 + wm * 32 + m * 16 + fq * 4 + q;
                const float sv = sb[(size_t)row * 128 + col];
                const float cv = fmaxf(acc[m][n][q] + cbias[col], 0.f);
                fused[((size_t)bb * L_ + row) * 128 + col] = sv * cv;
            }
        }
}

// ---------------------------------------------------------------------------
extern "C" void kernel_launch(void* const* d_in, const int* in_sizes, int n_in,
                              void* d_out, int out_size, void* d_ws, size_t ws_size,
                              hipStream_t stream)
{
    const float* x      = (const float*)d_in[0];
    const float* hprev  = (const float*)d_in[1];
    const float* A_log  = (const float*)d_in[2];
    const float* Dp     = (const float*)d_in[3];
    const float* W_x    = (const float*)d_in[4];
    const float* W_dt   = (const float*)d_in[5];
    const float* b_dt   = (const float*)d_in[6];
    const float* conv_w = (const float*)d_in[7];
    const float* conv_b = (const float*)d_in[8];
    const float* W_f    = (const float*)d_in[9];
    const float* b_f    = (const float*)d_in[10];

    float* out   = (float*)d_out;                       // fused_output
    float* h_out = out + (size_t)BL * D_;               // h_t

    float* ws    = (float*)d_ws;
    float* draw  = ws;                                  // delta_raw, later ssm
    float* delta = draw + (size_t)BL * D_;
    float* Bmb   = delta + (size_t)BL * D_;
    float* Cmb   = Bmb + (size_t)BL * N_;
    float* part  = Cmb + (size_t)BL * N_;
    float* negA  = part + (size_t)B_ * NC * D_;
    ushort_t* Wt0 = (ushort_t*)(negA + D_ * N_);
    ushort_t* Wt1 = Wt0 + 192 * 128;
    ushort_t* Wt2 = Wt1 + 128 * 128;
    ushort_t* Wtc = Wt2 + 128 * 128;
    float* ssm   = draw;                                // reuse (draw dead)

    // 0) weight transpose+convert, negA
    prep<<<dim3(24, 7), dim3(256), 0, stream>>>(
        W_x, W_dt, W_f, conv_w, A_log, Wt0, Wt1, Wt2, Wtc, negA);
    // 1) x_dbl = x @ W_x -> delta_raw | Bm | Cm
    gemm_mfma<192, 0><<<dim3(BL / 64), dim3(256), 0, stream>>>(
        x, Wt0, nullptr, draw, Bmb, Cmb);
    // 2) delta = softplus(delta_raw @ W_dt + b_dt)
    gemm_mfma<128, 1><<<dim3(BL / 64), dim3(256), 0, stream>>>(
        draw, Wt1, b_dt, delta, nullptr, nullptr);
    // 3-4) exclusive chunk prefix of delta over L
    scan_partial<<<dim3(NC, B_), dim3(128), 0, stream>>>(delta, part);
    scan_prefix<<<dim3(B_, D_), dim3(256), 0, stream>>>(part);
    // 5) selective-scan main: writes h_t
    scan_main<<<dim3(NC, B_), dim3(512), 0, stream>>>(
        delta, hprev, Bmb, Cmb, negA, Dp, part, h_out);
    // 6) ssm = relu(h_t @ W_f + b_f)
    gemm_mfma<128, 2><<<dim3(BL / 64), dim3(256), 0, stream>>>(
        h_out, Wt2, b_f, ssm, nullptr, nullptr);
    // 7) fused = ssm * relu(causal_conv3(ssm) + conv_b)
    conv_fuse_mfma<<<dim3(L_ / 64, B_), dim3(256), 0, stream>>>(
        ssm, Wtc, conv_b, out);
}

// Round 3
// 175.475 us; speedup vs baseline: 1.5392x; 1.0350x over previous
//
#include <hip/hip_runtime.h>
#include <math.h>

typedef unsigned short u16;
typedef __attribute__((ext_vector_type(8))) short short8v;   // 8 bf16
typedef __attribute__((ext_vector_type(4))) float f32x4;

constexpr int B_  = 4;
constexpr int L_  = 8192;
constexpr int D_  = 128;
constexpr int N_  = 32;
constexpr int BL  = B_ * L_;          // 32768 rows
constexpr int CH  = 16;               // part-chunk rows (gemm1 wave = 16 rows)
constexpr int NC  = L_ / CH;          // 512 chunks per batch
constexpr int SCH = 32;               // scan_main rows per block
constexpr int SNC = L_ / SCH;         // 256

// round-to-nearest-even f32 -> bf16
__device__ inline unsigned bfr(float x) {
    unsigned u = __float_as_uint(x);
    return (u + 0x7fffu + ((u >> 16) & 1u)) >> 16;
}
__device__ inline unsigned pkbf(float a, float b) { return bfr(a) | (bfr(b) << 16); }
__device__ inline float b2f(u16 h) { return __uint_as_float(((unsigned)h) << 16); }

// ---------------------------------------------------------------------------
// prep:
//  mode 0: W_eff^T = (W_x[:, :128] @ W_dt)^T -> Wt0 rows 0..127   (bf16 [n][k])
//  mode 1: W_x B/C cols^T -> Wt0 rows 128..191
//  mode 2: W_f^T -> Wt2
//  mode 3..5: conv tap w transposed -> Wtc[w]
//  mode 6: negA = -exp(A_log) * log2(e)   (for exp2-based scan)
// ---------------------------------------------------------------------------
__global__ __launch_bounds__(256) void prep(
    const float* __restrict__ Wx, const float* __restrict__ Wdt,
    const float* __restrict__ Wf, const float* __restrict__ Wconv,
    const float* __restrict__ A_log,
    u16* __restrict__ Wt0, u16* __restrict__ Wt2, u16* __restrict__ Wtc,
    float* __restrict__ negA)
{
    const int which = blockIdx.y;
    const int t = blockIdx.x * 256 + threadIdx.x;
    if (which == 0) {
        if (t >= 128 * 128) return;
        const int d = t >> 7, k = t & 127;        // write-coalesced in k
        float s = 0.f;
        for (int j = 0; j < 128; ++j)
            s = fmaf(Wx[(size_t)k * 192 + j], Wdt[(size_t)j * 128 + d], s);
        Wt0[d * 128 + k] = (u16)bfr(s);
    } else if (which == 1) {
        if (t >= 64 * 128) return;
        const int n = t >> 7, k = t & 127;
        Wt0[(128 + n) * 128 + k] = (u16)bfr(Wx[(size_t)k * 192 + 128 + n]);
    } else if (which == 2) {
        if (t >= 128 * 128) return;
        const int n = t >> 7, k = t & 127;
        Wt2[n * 128 + k] = (u16)bfr(Wf[(size_t)k * 128 + n]);
    } else if (which <= 5) {
        if (t >= 128 * 128) return;
        const int w = which - 3;
        const int n = t >> 7, k = t & 127;
        Wtc[((size_t)w * 128 + n) * 128 + k] = (u16)bfr(Wconv[((size_t)w * 128 + k) * 128 + n]);
    } else {
        if (t < D_ * N_) negA[t] = -expf(A_log[t]) * 1.4426950408889634f;
    }
}

// ---------------------------------------------------------------------------
// gemm1: x(BLx128) @ [W_eff | W_xB | W_xC] (128x192) with fused epilogue:
//   cols 0..127 : delta = softplus(v + b_dt) -> f32 delta, + per-16-row
//                 chunk column-sums -> part
//   cols 128..191: bc[l][j] = B[l][j] * C[l][j]  (product only)
// BM=64, 512 threads = 8 waves (wm 0..3 x wn 0..1), NF=6 per wave.
// ---------------------------------------------------------------------------
__global__ __launch_bounds__(512) void gemm1(
    const float* __restrict__ x, const u16* __restrict__ Wt0,
    const float* __restrict__ b_dt,
    float* __restrict__ delta, float* __restrict__ bc, float* __restrict__ part)
{
    __shared__ __align__(16) u16 Alds[64 * 64];    // 8 KB
    __shared__ __align__(16) u16 Blds[192 * 64];   // 24 KB

    const int tid = threadIdx.x;
    const int r0 = blockIdx.x * 64;                // global row base
    const int wid = tid >> 6, lane = tid & 63;
    const int wm = wid >> 1, wn = wid & 1;
    const int lr = lane & 15, kg = lane >> 4;

    f32x4 acc[6] = {};

    for (int kt = 0; kt < 128; kt += 64) {
        {   // stage A: 64 rows x 64 k, f32->bf16, swizzled
            const int row = tid >> 3, k8 = (tid & 7) * 8;
            const float* src = &x[(size_t)(r0 + row) * 128 + kt + k8];
            const float4 v0 = *reinterpret_cast<const float4*>(src);
            const float4 v1 = *reinterpret_cast<const float4*>(src + 4);
            uint4 p;
            p.x = pkbf(v0.x, v0.y); p.y = pkbf(v0.z, v0.w);
            p.z = pkbf(v1.x, v1.y); p.w = pkbf(v1.z, v1.w);
            *reinterpret_cast<uint4*>(&Alds[row * 64 + (k8 ^ ((row & 7) << 3))]) = p;
        }
        #pragma unroll
        for (int j = 0; j < 3; ++j) {  // stage B: 192 x 64 from bf16 global
            const int g = tid + j * 512;
            const int n = g >> 3, k8 = (g & 7) * 8;
            const uint4 p = *reinterpret_cast<const uint4*>(&Wt0[(size_t)n * 128 + kt + k8]);
            *reinterpret_cast<uint4*>(&Blds[n * 64 + (k8 ^ ((n & 7) << 3))]) = p;
        }
        __syncthreads();
        #pragma unroll
        for (int ks = 0; ks < 2; ++ks) {
            const int k8 = ks * 32 + kg * 8;
            const int row = wm * 16 + lr;
            const short8v af = *reinterpret_cast<const short8v*>(
                &Alds[row * 64 + (k8 ^ ((row & 7) << 3))]);
            #pragma unroll
            for (int nf = 0; nf < 6; ++nf) {
                const int col = wn * 96 + nf * 16 + lr;
                const short8v bf = *reinterpret_cast<const short8v*>(
                    &Blds[col * 64 + (k8 ^ ((col & 7) << 3))]);
                acc[nf] = __builtin_amdgcn_mfma_f32_16x16x32_bf16(af, bf, acc[nf], 0, 0, 0);
            }
        }
        __syncthreads();
    }

    // ---- epilogue ----
    const int nDelta = wn ? 2 : 6;          // frags that are delta columns
    float colsum[6];
    #pragma unroll
    for (int nf = 0; nf < 6; ++nf) {
        if (nf < nDelta) {
            const int col = wn * 96 + nf * 16 + lr;
            const float bb = b_dt[col];
            float s4 = 0.f;
            #pragma unroll
            for (int q = 0; q < 4; ++q) {
                float v = acc[nf][q] + bb;
                v = fmaxf(v, 0.f) + log1pf(expf(-fabsf(v)));   // stable softplus
                const int row = r0 + wm * 16 + kg * 4 + q;
                delta[(size_t)row * 128 + col] = v;
                s4 += v;
            }
            colsum[nf] = s4;
        }
    }
    if (wn) {   // bc product: frag2*frag4 -> j=lr, frag3*frag5 -> j=16+lr
        #pragma unroll
        for (int h = 0; h < 2; ++h)
            #pragma unroll
            for (int q = 0; q < 4; ++q) {
                const int row = r0 + wm * 16 + kg * 4 + q;
                bc[(size_t)row * 32 + h * 16 + lr] = acc[2 + h][q] * acc[4 + h][q];
            }
    }
    // chunk (16-row) column sums -> part
    const int b = r0 / L_;
    const int c = (r0 % L_) / CH + wm;
    #pragma unroll
    for (int nf = 0; nf < 6; ++nf) {
        if (nf < nDelta) {
            float s = colsum[nf];
            s += __shfl_xor(s, 16, 64);
            s += __shfl_xor(s, 32, 64);
            if (kg == 0) {
                const int col = wn * 96 + nf * 16 + lr;
                part[((size_t)b * NC + c) * 128 + col] = s;
            }
        }
    }
}

// ---------------------------------------------------------------------------
// scan_prefix: exclusive prefix over NC=512 chunks per (b,d). grid (B, D).
// ---------------------------------------------------------------------------
__global__ __launch_bounds__(512) void scan_prefix(float* __restrict__ part)
{
    const int b = blockIdx.x, d = blockIdx.y;
    const int c = threadIdx.x, w = c >> 6, lane = c & 63;
    const size_t idx = ((size_t)b * NC + c) * 128 + d;
    const float v = part[idx];
    float s = v;
    #pragma unroll
    for (int off = 1; off < 64; off <<= 1) {
        const float t = __shfl_up(s, off, 64);
        if (lane >= off) s += t;
    }
    __shared__ float wsum[8];
    if (lane == 63) wsum[w] = s;
    __syncthreads();
    float add = 0.f;
    #pragma unroll
    for (int i = 0; i < 8; ++i)
        if (i < w) add += wsum[i];
    part[idx] = s + add - v;   // exclusive
}

// ---------------------------------------------------------------------------
// scan_main (fused with W_f GEMM):
//  phase 1: stage delta tile (32x128 f32), bc tile (32x32 f32)
//  phase 2: per-thread exclusive prefix; h = (1+Dp)*dv*hv*sum_n bc*exp2(S*negA)
//           -> h_out (f32 global) + h_s (bf16 LDS, swizzled)
//  phase 3: ssm = relu(h @ W_f + b_f) via MFMA, W_f frags straight from L2
//           -> ssm bf16 global
// grid (SNC, B), 512 threads.
// ---------------------------------------------------------------------------
__global__ __launch_bounds__(512) void scan_main(
    const float* __restrict__ delta, const float* __restrict__ hprev,
    const float* __restrict__ bc, const float* __restrict__ negA,
    const float* __restrict__ Dp, const float* __restrict__ part,
    const u16* __restrict__ Wt2, const float* __restrict__ b_f,
    float* __restrict__ h_out, u16* __restrict__ ssm)
{
    __shared__ float delta_s[SCH][128];           // 16 KB
    __shared__ float bc_s[SCH][32];               // 4 KB
    __shared__ __align__(16) u16 h_s[SCH * 128];  // 8 KB, swizzled

    const int cb = blockIdx.x, b = blockIdx.y;
    const int tid = threadIdx.x;
    const size_t rowbase = (size_t)b * L_ + (size_t)cb * SCH;

    #pragma unroll
    for (int j = 0; j < 2; ++j) {     // delta tile: 1024 float4
        const int gg = tid + j * 512;
        const int row = gg >> 5, c4 = (gg & 31) * 4;
        *reinterpret_cast<float4*>(&delta_s[row][c4]) =
            *reinterpret_cast<const float4*>(&delta[(rowbase + row) * 128 + c4]);
    }
    if (tid < 256) {                  // bc tile: 256 float4
        const int row = tid >> 3, c4 = (tid & 7) * 4;
        *reinterpret_cast<float4*>(&bc_s[row][c4]) =
            *reinterpret_cast<const float4*>(&bc[(rowbase + row) * 32 + c4]);
    }

    const int d = tid & 127, r0 = tid >> 7;
    float a[N_];
    #pragma unroll
    for (int n4 = 0; n4 < 8; ++n4) {
        const float4 v = *reinterpret_cast<const float4*>(&negA[d * N_ + n4 * 4]);
        a[n4 * 4 + 0] = v.x; a[n4 * 4 + 1] = v.y;
        a[n4 * 4 + 2] = v.z; a[n4 * 4 + 3] = v.w;
    }
    const float dp1 = 1.f + Dp[d];
    float hv[8];
    #pragma unroll
    for (int r = 0; r < 8; ++r)
        hv[r] = hprev[(rowbase + r * 4 + r0) * 128 + d];
    const float sbase = part[((size_t)b * NC + cb * 2) * 128 + d];
    __syncthreads();

    float sv[8];
    {
        float s = sbase;
        #pragma unroll
        for (int i = 0; i < 32; ++i) {
            if ((i & 3) == r0) sv[i >> 2] = s;
            s += delta_s[i][d];
        }
    }
    #pragma unroll
    for (int r = 0; r < 8; ++r) {
        const int i = r * 4 + r0;
        const float dv = delta_s[i][d];
        const float sr = sv[r];
        float p0 = 0.f, p1 = 0.f, p2 = 0.f, p3 = 0.f;
        #pragma unroll
        for (int n = 0; n < N_; n += 4) {
            const float4 b4 = *reinterpret_cast<const float4*>(&bc_s[i][n]);
            p0 = fmaf(b4.x, exp2f(sr * a[n + 0]), p0);
            p1 = fmaf(b4.y, exp2f(sr * a[n + 1]), p1);
            p2 = fmaf(b4.z, exp2f(sr * a[n + 2]), p2);
            p3 = fmaf(b4.w, exp2f(sr * a[n + 3]), p3);
        }
        const float h = dv * hv[r] * ((p0 + p1) + (p2 + p3)) * dp1;
        h_out[(rowbase + i) * 128 + d] = h;
        h_s[i * 128 + (((d >> 3) ^ (i & 7)) << 3) + (d & 7)] = (u16)bfr(h);
    }
    __syncthreads();

    // phase 3: (32x128) @ W_f(128x128) + relu -> ssm bf16
    const int wid = tid >> 6, lane = tid & 63;
    const int lr = lane & 15, kg = lane >> 4;
    const int col = wid * 16 + lr;
    f32x4 acc[2] = {};
    #pragma unroll
    for (int ks = 0; ks < 4; ++ks) {
        const int k8 = ks * 32 + kg * 8;
        const short8v bfg = *reinterpret_cast<const short8v*>(&Wt2[(size_t)col * 128 + k8]);
        #pragma unroll
        for (int m = 0; m < 2; ++m) {
            const int row = m * 16 + lr;
            const short8v afg = *reinterpret_cast<const short8v*>(
                &h_s[row * 128 + (k8 ^ ((row & 7) << 3))]);
            acc[m] = __builtin_amdgcn_mfma_f32_16x16x32_bf16(afg, bfg, acc[m], 0, 0, 0);
        }
    }
    const float bb = b_f[col];
    #pragma unroll
    for (int m = 0; m < 2; ++m)
        #pragma unroll
        for (int q = 0; q < 4; ++q) {
            const int row = m * 16 + kg * 4 + q;
            const float v = fmaxf(acc[m][q] + bb, 0.f);
            ssm[(rowbase + row) * 128 + col] = (u16)bfr(v);
        }
}

// ---------------------------------------------------------------------------
// conv_fuse: fused = ssm * relu(causal_conv3(ssm) + conv_b)
// BM=128 (+2 halo), 512 threads = 8 waves; conv weights per-ks from L2 into
// VGPRs; epilogue multiply reads ssm bf16 back from the staged LDS tile.
// grid (L/128, B).
// ---------------------------------------------------------------------------
__global__ __launch_bounds__(512) void conv_fuse(
    const u16* __restrict__ ssm, const u16* __restrict__ Wtc,
    const float* __restrict__ cbias, float* __restrict__ fused)
{
    __shared__ __align__(16) u16 Alds[130 * 128];   // 33.3 KB, swizzled

    const int tid = threadIdx.x;
    const int bb = blockIdx.y;
    const int r0 = blockIdx.x * 128;               // row within batch
    const u16* sb = ssm + (size_t)bb * L_ * 128;

    #pragma unroll
    for (int j = 0; j < 5; ++j) {   // 130 rows x 16 groups = 2080
        const int g = tid + j * 512;
        if (g < 130 * 16) {
            const int i = g >> 4, k8 = (g & 15) * 8;
            const int gr = r0 - 2 + i;
            uint4 p = make_uint4(0, 0, 0, 0);
            if (gr >= 0)
                p = *reinterpret_cast<const uint4*>(&sb[(size_t)gr * 128 + k8]);
            *reinterpret_cast<uint4*>(&Alds[i * 128 + (k8 ^ ((i & 7) << 3))]) = p;
        }
    }
    __syncthreads();

    const int wid = tid >> 6, lane = tid & 63;
    const int wm = wid >> 1, wn = wid & 1;
    const int lr = lane & 15, kg = lane >> 4;

    f32x4 acc[2][4] = {};
    #pragma unroll
    for (int ks = 0; ks < 4; ++ks) {
        const int k8 = ks * 32 + kg * 8;
        short8v af[2][3];
        #pragma unroll
        for (int m = 0; m < 2; ++m)
            #pragma unroll
            for (int w = 0; w < 3; ++w) {
                const int ri = wm * 32 + m * 16 + lr + w;   // Alds row (halo-shifted)
                af[m][w] = *reinterpret_cast<const short8v*>(
                    &Alds[ri * 128 + (k8 ^ ((ri & 7) << 3))]);
            }
        #pragma unroll
        for (int nf = 0; nf < 4; ++nf) {
            const int col = wn * 64 + nf * 16 + lr;
            #pragma unroll
            for (int w = 0; w < 3; ++w) {
                const short8v bfg = *reinterpret_cast<const short8v*>(
                    &Wtc[((size_t)w * 128 + col) * 128 + k8]);
                acc[0][nf] = __builtin_amdgcn_mfma_f32_16x16x32_bf16(af[0][w], bfg, acc[0][nf], 0, 0, 0);
                acc[1][nf] = __builtin_amdgcn_mfma_f32_16x16x32_bf16(af[1][w], bfg, acc[1][nf], 0, 0, 0);
            }
        }
    }

    #pragma unroll
    for (int nf = 0; nf < 4; ++nf) {
        const int col = wn * 64 + nf * 16 + lr;
        const float bb2 = cbias[col];
        #pragma unroll
        for (int m = 0; m < 2; ++m)
            #pragma unroll
            for (int q = 0; q < 4; ++q) {
                const int row = wm * 32 + m * 16 + kg * 4 + q;
                const int ri = row + 2;
                const u16 sh = Alds[ri * 128 + ((((col >> 3) ^ (ri & 7)) << 3)) + (col & 7)];
                const float cv = fmaxf(acc[m][nf][q] + bb2, 0.f);
                fused[((size_t)bb * L_ + r0 + row) * 128 + col] = b2f(sh) * cv;
            }
    }
}

// ---------------------------------------------------------------------------
extern "C" void kernel_launch(void* const* d_in, const int* in_sizes, int n_in,
                              void* d_out, int out_size, void* d_ws, size_t ws_size,
                              hipStream_t stream)
{
    const float* x      = (const float*)d_in[0];
    const float* hprev  = (const float*)d_in[1];
    const float* A_log  = (const float*)d_in[2];
    const float* Dp     = (const float*)d_in[3];
    const float* W_x    = (const float*)d_in[4];
    const float* W_dt   = (const float*)d_in[5];
    const float* b_dt   = (const float*)d_in[6];
    const float* conv_w = (const float*)d_in[7];
    const float* conv_b = (const float*)d_in[8];
    const float* W_f    = (const float*)d_in[9];
    const float* b_f    = (const float*)d_in[10];

    float* out   = (float*)d_out;                       // fused_output
    float* h_out = out + (size_t)BL * D_;               // h_t

    char* ws = (char*)d_ws;
    float* delta = (float*)ws;                  ws += (size_t)BL * 128 * 4;
    float* bcb   = (float*)ws;                  ws += (size_t)BL * 32 * 4;
    float* part  = (float*)ws;                  ws += (size_t)B_ * NC * 128 * 4;
    float* negA  = (float*)ws;                  ws += (size_t)D_ * N_ * 4;
    u16*   Wt0   = (u16*)ws;                    ws += (size_t)192 * 128 * 2;
    u16*   Wt2   = (u16*)ws;                    ws += (size_t)128 * 128 * 2;
    u16*   Wtc   = (u16*)ws;                    ws += (size_t)3 * 128 * 128 * 2;
    u16*   ssm   = (u16*)ws;

    prep<<<dim3(64, 7), dim3(256), 0, stream>>>(
        W_x, W_dt, W_f, conv_w, A_log, Wt0, Wt2, Wtc, negA);
    gemm1<<<dim3(BL / 64), dim3(512), 0, stream>>>(
        x, Wt0, b_dt, delta, bcb, part);
    scan_prefix<<<dim3(B_, D_), dim3(512), 0, stream>>>(part);
    scan_main<<<dim3(SNC, B_), dim3(512), 0, stream>>>(
        delta, hprev, bcb, negA, Dp, part, Wt2, b_f, h_out, ssm);
    conv_fuse<<<dim3(L_ / 128, B_), dim3(512), 0, stream>>>(
        ssm, Wtc, conv_b, out);
}